// Round 6
// baseline (83.126 us; speedup 1.0000x reference)
//
#include <hip/hip_runtime.h>

#define WINDOW 128
#define H 32
#define O2 256
#define LFRAMES 65536
#define WU 32
#define FO_BLK 256     // output frames per block
#define FM 288         // mid (y-chain) frames per block
#define FS 320         // staged x frames per block

using bf16x8 = __attribute__((ext_vector_type(8))) short;
using f32x4  = __attribute__((ext_vector_type(4))) float;
using u16x4  = __attribute__((ext_vector_type(4))) unsigned short;

__device__ __forceinline__ unsigned bf16r(float v) {   // RTNE float->bf16 bits
    unsigned u = __builtin_bit_cast(unsigned, v);
    return (u + 0x7FFFu + ((u >> 16) & 1u)) >> 16;
}
__device__ __forceinline__ float bf2f(unsigned s) {
    return __builtin_bit_cast(float, s << 16);
}
__device__ __forceinline__ float selu_f(float x) {
    const float scale = 1.0507009873554805f;
    const float alpha = 1.6732632423543772f;
    return scale * (x > 0.0f ? x : alpha * (expf(x) - 1.0f));
}
__device__ __forceinline__ bf16x8 cvt8(float4 a, float4 b) {
    bf16x8 r;
    r[0] = (short)bf16r(a.x); r[1] = (short)bf16r(a.y);
    r[2] = (short)bf16r(a.z); r[3] = (short)bf16r(a.w);
    r[4] = (short)bf16r(b.x); r[5] = (short)bf16r(b.y);
    r[6] = (short)bf16r(b.z); r[7] = (short)bf16r(b.w);
    return r;
}

// ---------------- fused-kernel LDS byte offsets (total 159872 <= 160KiB) ----
#define OFF_LAM1   0        // [32 taps][64 f32]                       (8192)
#define OFF_LAM2   8192     //                                         (8192)
#define OFF_C1HI   16384    // [32][72] bf16, pitch 144B               (4608)
#define OFF_C1LO   20992
#define OFF_MWHI   25600    // [32][40] bf16, pitch 80B                (2560)
#define OFF_MWLO   28160
#define OFF_B2HI   30720    // [64][40] bf16, pitch 80B                (5120)
#define OFF_B2LO   35840
#define OFF_BIAS   40960    // [32] f32                                (128)
#define OFF_P      41088    // u1 [320][68]bf16 p136 | y1s [288][40]p80 | u2s [288][68]p136
#define OFF_D      84608    // d1x [288][40]bf16 p80 | y2l [288][40]bf16 p80
#define OFF_W      107648   // W1HI [96][136]bf16 p272 (26112) + W1LO | h1 [288][72]p144 | h2 [256][72]p144
#define OFF_W1LO   133760
#define S_LDS      159872

// ---------------------------------------------------------------------------
// prep: wcat (256 x 96) bf16 hi/lo. k<64: even->c2r, odd->-c2i; k>=64: d2.
// ---------------------------------------------------------------------------
__global__ void prep_wcat(const float* __restrict__ c2r, const float* __restrict__ c2i,
                          const float* __restrict__ d2,
                          unsigned short* __restrict__ whi, unsigned short* __restrict__ wlo)
{
    int idx = blockIdx.x * 256 + threadIdx.x;
    if (idx >= O2 * 96) return;
    int row = idx / 96, k = idx - row * 96;
    float v;
    if (k < 64) v = (k & 1) ? -c2i[row * H + (k >> 1)] : c2r[row * H + (k >> 1)];
    else        v = d2[row * H + (k - 64)];
    unsigned h = bf16r(v);
    whi[idx] = (unsigned short)h;
    wlo[idx] = (unsigned short)bf16r(v - bf2f(h));
}

// ---------------------------------------------------------------------------
// Fused kernel: x -> out, everything in LDS. 256 blocks x 1024 threads.
// 16 waves/block = 4 waves/SIMD for latency hiding.
// ---------------------------------------------------------------------------
__global__ __launch_bounds__(1024, 1)
void lru_fused(const float* __restrict__ x,
               const float* __restrict__ b1r, const float* __restrict__ b1i,
               const float* __restrict__ nu1, const float* __restrict__ th1,
               const float* __restrict__ c1r, const float* __restrict__ c1i,
               const float* __restrict__ d1,
               const float* __restrict__ mlp_w, const float* __restrict__ mlp_b,
               const float* __restrict__ b2r, const float* __restrict__ b2i,
               const float* __restrict__ nu2, const float* __restrict__ th2,
               const unsigned short* __restrict__ whi, const unsigned short* __restrict__ wlo,
               float* __restrict__ out)
{
    __shared__ __align__(16) char smem[S_LDS];
    const int tid = threadIdx.x;
    const int t0 = blockIdx.x * FO_BLK;
    const int frame0 = t0 - 64;              // global frame of staged idx 0
    const int w = tid >> 6, l = tid & 63, l15 = l & 15, lq = l >> 4;

    // ================= phase 0: weights -> LDS, lambda tables =================
    if (tid < H) {
        {
            float enu = expf(nu1[tid]);
            float mag = expf(-enu);
            float ang = expf(th1[tid]);
            float lr = mag * cosf(ang), li = mag * sinf(ang);
            float g = sqrtf(fmaxf(1.0f - mag * mag, 0.0f));
            float pr = g, pi = 0.0f;
            float* lam = (float*)(smem + OFF_LAM1);
            for (int j = 0; j < WU; ++j) {
                lam[j * 64 + 2 * tid] = pr;
                lam[j * 64 + 2 * tid + 1] = pi;
                float npr = pr * lr - pi * li, npi = pr * li + pi * lr;
                pr = npr; pi = npi;
            }
        }
        {
            float enu = expf(nu2[tid]);
            float mag = expf(-enu);
            float ang = expf(th2[tid]);
            float lr = mag * cosf(ang), li = mag * sinf(ang);
            float g = sqrtf(fmaxf(1.0f - mag * mag, 0.0f));
            float pr = g, pi = 0.0f;
            float* lam = (float*)(smem + OFF_LAM2);
            for (int j = 0; j < WU; ++j) {
                lam[j * 64 + 2 * tid] = pr;
                lam[j * 64 + 2 * tid + 1] = pi;
                float npr = pr * lr - pi * li, npi = pr * li + pi * lr;
                pr = npr; pi = npi;
            }
        }
        ((float*)(smem + OFF_BIAS))[tid] = mlp_b[tid];
    }
    // W1: rows 0..63 interleaved (2c=b1r[c], 2c+1=b1i[c]), rows 64..95 = d1
    {
        unsigned short* hi = (unsigned short*)(smem + OFF_W);
        unsigned short* lo = (unsigned short*)(smem + OFF_W1LO);
        #pragma unroll
        for (int p = 0; p < 12; ++p) {
            int idx = tid + 1024 * p;
            int row = idx >> 7, k = idx & 127;
            float v;
            if (row < 64) v = (row & 1) ? b1i[(row >> 1) * WINDOW + k] : b1r[(row >> 1) * WINDOW + k];
            else          v = d1[(row - 64) * WINDOW + k];
            unsigned h = bf16r(v);
            hi[row * 136 + k] = (unsigned short)h;
            lo[row * 136 + k] = (unsigned short)bf16r(v - bf2f(h));
        }
    }
    // C1cat: [32][64], k even -> c1r, k odd -> -c1i
    {
        unsigned short* hi = (unsigned short*)(smem + OFF_C1HI);
        unsigned short* lo = (unsigned short*)(smem + OFF_C1LO);
        #pragma unroll
        for (int p = 0; p < 2; ++p) {
            int idx = tid + 1024 * p;
            int row = idx >> 6, k = idx & 63;
            float v = (k & 1) ? -c1i[row * H + (k >> 1)] : c1r[row * H + (k >> 1)];
            unsigned h = bf16r(v);
            hi[row * 72 + k] = (unsigned short)h;
            lo[row * 72 + k] = (unsigned short)bf16r(v - bf2f(h));
        }
    }
    // mlpw^T
    {
        unsigned short* hi = (unsigned short*)(smem + OFF_MWHI);
        unsigned short* lo = (unsigned short*)(smem + OFF_MWLO);
        int row = tid >> 5, k = tid & 31;
        float v = mlp_w[k * H + row];
        unsigned h = bf16r(v);
        hi[row * 40 + k] = (unsigned short)h;
        lo[row * 40 + k] = (unsigned short)bf16r(v - bf2f(h));
    }
    // b2cat: rows interleaved (2c=b2r[c], 2c+1=b2i[c]), K=32
    {
        unsigned short* hi = (unsigned short*)(smem + OFF_B2HI);
        unsigned short* lo = (unsigned short*)(smem + OFF_B2LO);
        #pragma unroll
        for (int p = 0; p < 2; ++p) {
            int idx = tid + 1024 * p;
            int row = idx >> 5, k = idx & 31;
            float v = (row & 1) ? b2i[(row >> 1) * H + k] : b2r[(row >> 1) * H + k];
            unsigned h = bf16r(v);
            hi[row * 40 + k] = (unsigned short)h;
            lo[row * 40 + k] = (unsigned short)bf16r(v - bf2f(h));
        }
    }
    __syncthreads();

    // ================= GEMM1: U1 (96 x 320) = W1 @ X =========================
    // 20 N-tiles; wave w owns {w, w+16} (guard nt<20). m split into 2 halves
    // of 3 rows to cap VGPR pressure at 4 waves/SIMD.
    {
        f32x4 acc1[2][6];
        #pragma unroll
        for (int ni = 0; ni < 2; ++ni)
            #pragma unroll
            for (int m = 0; m < 6; ++m) acc1[ni][m] = f32x4{0.f, 0.f, 0.f, 0.f};

        #pragma unroll 1
        for (int ks = 0; ks < 4; ++ks) {
            bf16x8 bfrag[2];
            #pragma unroll
            for (int ni = 0; ni < 2; ++ni) {
                int nt = w + ni * 16;
                if (nt < 20) {
                    int gf = frame0 + nt * 16 + l15;
                    float4 xa{}, xb{};
                    if (gf >= 0) {
                        const float4* xp = (const float4*)(x + (size_t)gf * WINDOW + ks * 32 + lq * 8);
                        xa = xp[0]; xb = xp[1];
                    }
                    bfrag[ni] = cvt8(xa, xb);
                }
            }
            #pragma unroll 1
            for (int mh = 0; mh < 2; ++mh) {
                bf16x8 ah[3], al[3];
                #pragma unroll
                for (int mm = 0; mm < 3; ++mm) {
                    int ro = ((mh * 3 + mm) * 16 + l15) * 272 + ks * 64 + lq * 16;
                    ah[mm] = *(const bf16x8*)(smem + OFF_W + ro);
                    al[mm] = *(const bf16x8*)(smem + OFF_W1LO + ro);
                }
                #pragma unroll
                for (int ni = 0; ni < 2; ++ni) {
                    int nt = w + ni * 16;
                    if (nt < 20) {
                        #pragma unroll
                        for (int mm = 0; mm < 3; ++mm) {
                            int m = mh * 3 + mm;
                            acc1[ni][m] = __builtin_amdgcn_mfma_f32_16x16x32_bf16(ah[mm], bfrag[ni], acc1[ni][m], 0, 0, 0);
                            acc1[ni][m] = __builtin_amdgcn_mfma_f32_16x16x32_bf16(al[mm], bfrag[ni], acc1[ni][m], 0, 0, 0);
                        }
                    }
                }
            }
        }
        // epilogue: rows 0..63 -> u1 (P, all 320 frames); 64..95 -> d1x bf16 (288 mid)
        #pragma unroll
        for (int ni = 0; ni < 2; ++ni) {
            int nt = w + ni * 16;
            if (nt < 20) {
                int fs = nt * 16 + l15;
                #pragma unroll
                for (int m = 0; m < 4; ++m) {
                    u16x4 pk;
                    #pragma unroll
                    for (int j = 0; j < 4; ++j) pk[j] = (unsigned short)bf16r(acc1[ni][m][j]);
                    *(u16x4*)(smem + OFF_P + fs * 136 + (m * 16 + lq * 4) * 2) = pk;
                }
                if (fs >= 32) {
                    int fm = fs - 32;
                    #pragma unroll
                    for (int m = 4; m < 6; ++m) {
                        u16x4 pk;
                        #pragma unroll
                        for (int j = 0; j < 4; ++j) pk[j] = (unsigned short)bf16r(acc1[ni][m][j]);
                        *(u16x4*)(smem + OFF_D + fm * 80 + ((m - 4) * 16 + lq * 4) * 2) = pk;
                    }
                }
            }
        }
    }
    __syncthreads();

    // ================= conv1: 288 mid states -> h1 (bf16) ====================
    {
        int c = tid & 31, g = tid >> 5;          // 32 groups x 9 frames
        float enu = expf(nu1[c]);
        float mag = expf(-enu);
        float ang = expf(th1[c]);
        float lr = mag * cosf(ang), li = mag * sinf(ang);
        float gam = sqrtf(fmaxf(1.0f - mag * mag, 0.0f));
        const float* lam = (const float*)(smem + OFF_LAM1);
        int fmb = g * 9;
        float hre = 0.f, him = 0.f;
        for (int j = 0; j < WU; ++j) {
            float2 lp = *(const float2*)(lam + j * 64 + 2 * c);
            unsigned uw = *(const unsigned*)(smem + OFF_P + (fmb + 32 - j) * 136 + c * 4);
            float ur = bf2f(uw & 0xFFFFu), ui = bf2f(uw >> 16);
            hre = fmaf(lp.x, ur, hre); hre = fmaf(-lp.y, ui, hre);
            him = fmaf(lp.x, ui, him); him = fmaf(lp.y, ur, him);
        }
        *(unsigned*)(smem + OFF_W + fmb * 144 + c * 4) = (bf16r(him) << 16) | bf16r(hre);
        for (int s = 1; s < 9; ++s) {
            unsigned uw = *(const unsigned*)(smem + OFF_P + (fmb + 32 + s) * 136 + c * 4);
            float ur = bf2f(uw & 0xFFFFu), ui = bf2f(uw >> 16);
            float nre = lr * hre - li * him + gam * ur;
            float nim = lr * him + li * hre + gam * ui;
            hre = nre; him = nim;
            *(unsigned*)(smem + OFF_W + (fmb + s) * 144 + c * 4) = (bf16r(him) << 16) | bf16r(hre);
        }
    }
    __syncthreads();

    // ================= GEMM2: y1 = C1cat @ h1 + d1x ; selu -> y1s ============
    #pragma unroll 1
    for (int ci = w; ci < 36; ci += 16) {
        int n = ci >> 1, m = ci & 1;
        int fcol = n * 16 + l15;
        u16x4 dk = *(const u16x4*)(smem + OFF_D + fcol * 80 + (m * 16 + lq * 4) * 2);
        f32x4 c;
        #pragma unroll
        for (int j = 0; j < 4; ++j) c[j] = bf2f(dk[j]);
        #pragma unroll
        for (int ks = 0; ks < 2; ++ks) {
            int ao = (m * 16 + l15) * 144 + ks * 64 + lq * 16;
            bf16x8 ah = *(const bf16x8*)(smem + OFF_C1HI + ao);
            bf16x8 al = *(const bf16x8*)(smem + OFF_C1LO + ao);
            bf16x8 bb = *(const bf16x8*)(smem + OFF_W + fcol * 144 + ks * 64 + lq * 16);
            c = __builtin_amdgcn_mfma_f32_16x16x32_bf16(ah, bb, c, 0, 0, 0);
            c = __builtin_amdgcn_mfma_f32_16x16x32_bf16(al, bb, c, 0, 0, 0);
        }
        u16x4 pk;
        #pragma unroll
        for (int j = 0; j < 4; ++j) pk[j] = (unsigned short)bf16r(selu_f(c[j]));
        *(u16x4*)(smem + OFF_P + fcol * 80 + (m * 16 + lq * 4) * 2) = pk;
    }
    __syncthreads();

    // ================= MLP: y2 = mlpw^T @ y1s + bias ; selu -> y2l ===========
    #pragma unroll 1
    for (int ci = w; ci < 36; ci += 16) {
        int n = ci >> 1, m = ci & 1;
        int fcol = n * 16 + l15;
        f32x4 c = *(const f32x4*)(smem + OFF_BIAS + (m * 16 + lq * 4) * 4);
        {
            int ao = (m * 16 + l15) * 80 + lq * 16;
            bf16x8 ah = *(const bf16x8*)(smem + OFF_MWHI + ao);
            bf16x8 al = *(const bf16x8*)(smem + OFF_MWLO + ao);
            bf16x8 bb = *(const bf16x8*)(smem + OFF_P + fcol * 80 + lq * 16);
            c = __builtin_amdgcn_mfma_f32_16x16x32_bf16(ah, bb, c, 0, 0, 0);
            c = __builtin_amdgcn_mfma_f32_16x16x32_bf16(al, bb, c, 0, 0, 0);
        }
        u16x4 pk;
        #pragma unroll
        for (int j = 0; j < 4; ++j) pk[j] = (unsigned short)bf16r(selu_f(c[j]));
        *(u16x4*)(smem + OFF_D + fcol * 80 + (m * 16 + lq * 4) * 2) = pk;
    }
    __syncthreads();

    // ================= GEMM3: u2 = b2cat @ y2l -> u2s (bf16) =================
    #pragma unroll 1
    for (int ci = w; ci < 72; ci += 16) {
        int n = ci >> 2, m = ci & 3;
        int fcol = n * 16 + l15;
        f32x4 c = f32x4{0.f, 0.f, 0.f, 0.f};
        {
            int ao = (m * 16 + l15) * 80 + lq * 16;
            bf16x8 ah = *(const bf16x8*)(smem + OFF_B2HI + ao);
            bf16x8 al = *(const bf16x8*)(smem + OFF_B2LO + ao);
            bf16x8 bb = *(const bf16x8*)(smem + OFF_D + fcol * 80 + lq * 16);
            c = __builtin_amdgcn_mfma_f32_16x16x32_bf16(ah, bb, c, 0, 0, 0);
            c = __builtin_amdgcn_mfma_f32_16x16x32_bf16(al, bb, c, 0, 0, 0);
        }
        if (t0 - 32 + fcol < 0) c = f32x4{0.f, 0.f, 0.f, 0.f};   // pre-history is zero
        u16x4 pk;
        #pragma unroll
        for (int j = 0; j < 4; ++j) pk[j] = (unsigned short)bf16r(c[j]);
        *(u16x4*)(smem + OFF_P + fcol * 136 + (m * 16 + lq * 4) * 2) = pk;
    }
    __syncthreads();

    // ================= conv2: 256 out states -> h2 (bf16) ====================
    {
        int c = tid & 31, g = tid >> 5;          // 32 groups x 8 frames
        float enu = expf(nu2[c]);
        float mag = expf(-enu);
        float ang = expf(th2[c]);
        float lr = mag * cosf(ang), li = mag * sinf(ang);
        float gam = sqrtf(fmaxf(1.0f - mag * mag, 0.0f));
        const float* lam = (const float*)(smem + OFF_LAM2);
        int fob = g * 8;
        float hre = 0.f, him = 0.f;
        for (int j = 0; j < WU; ++j) {
            float2 lp = *(const float2*)(lam + j * 64 + 2 * c);
            unsigned uw = *(const unsigned*)(smem + OFF_P + (fob + 32 - j) * 136 + c * 4);
            float ur = bf2f(uw & 0xFFFFu), ui = bf2f(uw >> 16);
            hre = fmaf(lp.x, ur, hre); hre = fmaf(-lp.y, ui, hre);
            him = fmaf(lp.x, ui, him); him = fmaf(lp.y, ur, him);
        }
        *(unsigned*)(smem + OFF_W + fob * 144 + c * 4) = (bf16r(him) << 16) | bf16r(hre);
        for (int s = 1; s < 8; ++s) {
            unsigned uw = *(const unsigned*)(smem + OFF_P + (fob + 32 + s) * 136 + c * 4);
            float ur = bf2f(uw & 0xFFFFu), ui = bf2f(uw >> 16);
            float nre = lr * hre - li * him + gam * ur;
            float nim = lr * him + li * hre + gam * ui;
            hre = nre; him = nim;
            *(unsigned*)(smem + OFF_W + (fob + s) * 144 + c * 4) = (bf16r(him) << 16) | bf16r(hre);
        }
    }
    __syncthreads();

    // ================= GEMM4: out = wcat @ [h2 ; y2] ==========================
    // wave w owns M-tile w (16 rows); A-frags preloaded for all 3 ks;
    // N-outer with store-as-you-go spreads the HBM writes over the phase.
    {
        const int row = w * 16 + l15;
        bf16x8 ah[3], al[3];
        #pragma unroll
        for (int ks = 0; ks < 3; ++ks) {
            ah[ks] = *(const bf16x8*)(whi + row * 96 + ks * 32 + lq * 8);
            al[ks] = *(const bf16x8*)(wlo + row * 96 + ks * 32 + lq * 8);
        }
        const int row0 = w * 16 + lq * 4;
        #pragma unroll 1
        for (int n = 0; n < 16; ++n) {
            int fcol = n * 16 + l15;
            f32x4 c = f32x4{0.f, 0.f, 0.f, 0.f};
            #pragma unroll
            for (int ks = 0; ks < 3; ++ks) {
                bf16x8 bb;
                if (ks < 2) bb = *(const bf16x8*)(smem + OFF_W + fcol * 144 + ks * 64 + lq * 16);
                else        bb = *(const bf16x8*)(smem + OFF_D + (fcol + 32) * 80 + lq * 16);
                c = __builtin_amdgcn_mfma_f32_16x16x32_bf16(ah[ks], bb, c, 0, 0, 0);
                c = __builtin_amdgcn_mfma_f32_16x16x32_bf16(al[ks], bb, c, 0, 0, 0);
            }
            int t = t0 + n * 16 + l15;
            #pragma unroll
            for (int j = 0; j < 4; ++j)
                out[(size_t)(row0 + j) * LFRAMES + t] = c[j];
        }
    }
}

extern "C" void kernel_launch(void* const* d_in, const int* in_sizes, int n_in,
                              void* d_out, int out_size, void* d_ws, size_t ws_size,
                              hipStream_t stream)
{
    const float* x     = (const float*)d_in[0];
    const float* b1r   = (const float*)d_in[1];
    const float* b1i   = (const float*)d_in[2];
    const float* nu1   = (const float*)d_in[3];
    const float* th1   = (const float*)d_in[4];
    const float* c1r   = (const float*)d_in[5];
    const float* c1i   = (const float*)d_in[6];
    const float* d1    = (const float*)d_in[7];
    const float* mlp_w = (const float*)d_in[8];
    const float* mlp_b = (const float*)d_in[9];
    const float* b2r   = (const float*)d_in[10];
    const float* b2i   = (const float*)d_in[11];
    const float* nu2   = (const float*)d_in[12];
    const float* th2   = (const float*)d_in[13];
    const float* c2r   = (const float*)d_in[14];
    const float* c2i   = (const float*)d_in[15];
    const float* d2    = (const float*)d_in[16];
    float* out = (float*)d_out;

    unsigned short* whi = (unsigned short*)d_ws;                      // 49,152 B
    unsigned short* wlo = (unsigned short*)((char*)d_ws + 49152);     // 49,152 B

    prep_wcat<<<dim3((O2 * 96 + 255) / 256), dim3(256), 0, stream>>>(c2r, c2i, d2, whi, wlo);

    lru_fused<<<dim3(LFRAMES / FO_BLK), dim3(1024), 0, stream>>>(
        x, b1r, b1i, nu1, th1, c1r, c1i, d1, mlp_w, mlp_b,
        b2r, b2i, nu2, th2, whi, wlo, out);
}

// Round 7
// 45.928 us; speedup vs baseline: 1.8099x; 1.8099x over previous
//
#include <hip/hip_runtime.h>

#define WINDOW 128
#define H 32
#define O2 256
#define LFRAMES 65536
#define WU 32
#define FO_BLK 256     // output frames per block
#define FM 288         // mid (y-chain) frames per block
#define FS 320         // staged x frames per block

using bf16x8 = __attribute__((ext_vector_type(8))) short;
using f32x4  = __attribute__((ext_vector_type(4))) float;
using u16x4  = __attribute__((ext_vector_type(4))) unsigned short;

__device__ __forceinline__ unsigned bf16r(float v) {   // RTNE float->bf16 bits
    unsigned u = __builtin_bit_cast(unsigned, v);
    return (u + 0x7FFFu + ((u >> 16) & 1u)) >> 16;
}
__device__ __forceinline__ float bf2f(unsigned s) {
    return __builtin_bit_cast(float, s << 16);
}
__device__ __forceinline__ float selu_f(float x) {
    const float scale = 1.0507009873554805f;
    const float alpha = 1.6732632423543772f;
    return scale * (x > 0.0f ? x : alpha * (expf(x) - 1.0f));
}
__device__ __forceinline__ bf16x8 cvt8(float4 a, float4 b) {
    bf16x8 r;
    r[0] = (short)bf16r(a.x); r[1] = (short)bf16r(a.y);
    r[2] = (short)bf16r(a.z); r[3] = (short)bf16r(a.w);
    r[4] = (short)bf16r(b.x); r[5] = (short)bf16r(b.y);
    r[6] = (short)bf16r(b.z); r[7] = (short)bf16r(b.w);
    return r;
}

// ---------------- fused-kernel LDS byte offsets (total 136832) --------------
#define OFF_LAM1   0        // [32 taps][64 f32]                  (8192)
#define OFF_LAM2   8192     //                                    (8192)
#define OFF_C1HI   16384    // [32][72] bf16, pitch 144B          (4608)
#define OFF_MWHI   20992    // [32][40] bf16, pitch 80B           (2560)
#define OFF_B2HI   23552    // [64][40] bf16, pitch 80B           (5120)
#define OFF_BIAS   28672    // [32] f32                           (128)
#define OFF_P      28800    // u1 [320]p136 (43520) | y1s [288]p80 | u2s [288]p136
#define OFF_D      72320    // d1x [288]p80 (23040) | y2l [288]p80
#define OFF_W      95360    // W1HI [96]p272 (26112) | h1 [288]p144 (41472) | h2 [256]p144
#define S_LDS      136832

// ---------------------------------------------------------------------------
// prep: wcat (256 x 96) bf16 hi/lo. k<64: even->c2r, odd->-c2i; k>=64: d2.
// ---------------------------------------------------------------------------
__global__ void prep_wcat(const float* __restrict__ c2r, const float* __restrict__ c2i,
                          const float* __restrict__ d2,
                          unsigned short* __restrict__ whi, unsigned short* __restrict__ wlo)
{
    int idx = blockIdx.x * 256 + threadIdx.x;
    if (idx >= O2 * 96) return;
    int row = idx / 96, k = idx - row * 96;
    float v;
    if (k < 64) v = (k & 1) ? -c2i[row * H + (k >> 1)] : c2r[row * H + (k >> 1)];
    else        v = d2[row * H + (k - 64)];
    unsigned h = bf16r(v);
    whi[idx] = (unsigned short)h;
    wlo[idx] = (unsigned short)bf16r(v - bf2f(h));
}

// ---------------------------------------------------------------------------
// Fused kernel: x -> out, everything in LDS. 256 blocks x 1024 threads.
// 16 waves/block = 4 waves/SIMD. All register arrays statically indexed.
// ---------------------------------------------------------------------------
__global__ __launch_bounds__(1024, 1)
void lru_fused(const float* __restrict__ x,
               const float* __restrict__ b1r, const float* __restrict__ b1i,
               const float* __restrict__ nu1, const float* __restrict__ th1,
               const float* __restrict__ c1r, const float* __restrict__ c1i,
               const float* __restrict__ d1,
               const float* __restrict__ mlp_w, const float* __restrict__ mlp_b,
               const float* __restrict__ b2r, const float* __restrict__ b2i,
               const float* __restrict__ nu2, const float* __restrict__ th2,
               const unsigned short* __restrict__ whi, const unsigned short* __restrict__ wlo,
               float* __restrict__ out)
{
    __shared__ __align__(16) char smem[S_LDS];
    const int tid = threadIdx.x;
    const int t0 = blockIdx.x * FO_BLK;
    const int frame0 = t0 - 64;              // global frame of staged idx 0
    const int w = tid >> 6, l = tid & 63, l15 = l & 15, lq = l >> 4;

    // ================= phase 0: weights -> LDS, lambda tables =================
    if (tid < 64) {
        int c = tid & 31;
        const float* nu = (tid < 32) ? nu1 : nu2;
        const float* th = (tid < 32) ? th1 : th2;
        float* lam = (float*)(smem + ((tid < 32) ? OFF_LAM1 : OFF_LAM2));
        float enu = expf(nu[c]);
        float mag = expf(-enu);
        float ang = expf(th[c]);
        float lr = mag * cosf(ang), li = mag * sinf(ang);
        float g = sqrtf(fmaxf(1.0f - mag * mag, 0.0f));
        float pr = g, pi = 0.0f;
        for (int j = 0; j < WU; ++j) {
            lam[j * 64 + 2 * c]     = pr;
            lam[j * 64 + 2 * c + 1] = pi;
            float npr = pr * lr - pi * li, npi = pr * li + pi * lr;
            pr = npr; pi = npi;
        }
    } else if (tid >= 64 && tid < 96) {
        ((float*)(smem + OFF_BIAS))[tid - 64] = mlp_b[tid - 64];
    }
    // W1 (hi only): rows 0..63 interleaved (2c=b1r[c], 2c+1=b1i[c]), 64..95 = d1
    {
        unsigned short* hi = (unsigned short*)(smem + OFF_W);
        #pragma unroll
        for (int p = 0; p < 12; ++p) {
            int idx = tid + 1024 * p;
            int row = idx >> 7, k = idx & 127;
            float v;
            if (row < 64) v = (row & 1) ? b1i[(row >> 1) * WINDOW + k] : b1r[(row >> 1) * WINDOW + k];
            else          v = d1[(row - 64) * WINDOW + k];
            hi[row * 136 + k] = (unsigned short)bf16r(v);
        }
    }
    // C1cat (hi): [32][64], k even -> c1r, k odd -> -c1i
    {
        unsigned short* hi = (unsigned short*)(smem + OFF_C1HI);
        #pragma unroll
        for (int p = 0; p < 2; ++p) {
            int idx = tid + 1024 * p;
            int row = idx >> 6, k = idx & 63;
            float v = (k & 1) ? -c1i[row * H + (k >> 1)] : c1r[row * H + (k >> 1)];
            hi[row * 72 + k] = (unsigned short)bf16r(v);
        }
    }
    // mlpw^T (hi)
    {
        unsigned short* hi = (unsigned short*)(smem + OFF_MWHI);
        int row = tid >> 5, k = tid & 31;
        if (tid < 1024) hi[row * 40 + k] = (unsigned short)bf16r(mlp_w[k * H + row]);
    }
    // b2cat (hi): rows interleaved (2c=b2r[c], 2c+1=b2i[c]), K=32
    {
        unsigned short* hi = (unsigned short*)(smem + OFF_B2HI);
        #pragma unroll
        for (int p = 0; p < 2; ++p) {
            int idx = tid + 1024 * p;
            int row = idx >> 5, k = idx & 31;
            float v = (row & 1) ? b2i[(row >> 1) * H + k] : b2r[(row >> 1) * H + k];
            hi[row * 40 + k] = (unsigned short)bf16r(v);
        }
    }
    __syncthreads();

    // ================= GEMM1: U1 (96 x 320) = W1 @ X =========================
    // 20 N-tiles over 16 waves: wave w does nt = w (+16 for w<4).
    #pragma unroll 1
    for (int nt = w; nt < 20; nt += 16) {
        f32x4 a0 = f32x4{0.f,0.f,0.f,0.f}, a1 = a0, a2 = a0, a3 = a0, a4 = a0, a5 = a0;
        int gf = frame0 + nt * 16 + l15;
        const float4* xp = (const float4*)(x + (size_t)gf * WINDOW + lq * 8);
        #pragma unroll
        for (int ks = 0; ks < 4; ++ks) {
            float4 xa{}, xb{};
            if (gf >= 0) { xa = xp[ks * 8]; xb = xp[ks * 8 + 1]; }
            bf16x8 b = cvt8(xa, xb);
            bf16x8 w0 = *(const bf16x8*)(smem + OFF_W + (0 * 16 + l15) * 272 + ks * 64 + lq * 16);
            bf16x8 w1 = *(const bf16x8*)(smem + OFF_W + (1 * 16 + l15) * 272 + ks * 64 + lq * 16);
            bf16x8 w2 = *(const bf16x8*)(smem + OFF_W + (2 * 16 + l15) * 272 + ks * 64 + lq * 16);
            bf16x8 w3 = *(const bf16x8*)(smem + OFF_W + (3 * 16 + l15) * 272 + ks * 64 + lq * 16);
            bf16x8 w4 = *(const bf16x8*)(smem + OFF_W + (4 * 16 + l15) * 272 + ks * 64 + lq * 16);
            bf16x8 w5 = *(const bf16x8*)(smem + OFF_W + (5 * 16 + l15) * 272 + ks * 64 + lq * 16);
            a0 = __builtin_amdgcn_mfma_f32_16x16x32_bf16(w0, b, a0, 0, 0, 0);
            a1 = __builtin_amdgcn_mfma_f32_16x16x32_bf16(w1, b, a1, 0, 0, 0);
            a2 = __builtin_amdgcn_mfma_f32_16x16x32_bf16(w2, b, a2, 0, 0, 0);
            a3 = __builtin_amdgcn_mfma_f32_16x16x32_bf16(w3, b, a3, 0, 0, 0);
            a4 = __builtin_amdgcn_mfma_f32_16x16x32_bf16(w4, b, a4, 0, 0, 0);
            a5 = __builtin_amdgcn_mfma_f32_16x16x32_bf16(w5, b, a5, 0, 0, 0);
        }
        // epilogue: rows 0..63 -> u1 (P); rows 64..95 -> d1x (D, mid frames)
        int fs = nt * 16 + l15;
        {
            u16x4 p0, p1, p2, p3;
            #pragma unroll
            for (int j = 0; j < 4; ++j) {
                p0[j] = (unsigned short)bf16r(a0[j]);
                p1[j] = (unsigned short)bf16r(a1[j]);
                p2[j] = (unsigned short)bf16r(a2[j]);
                p3[j] = (unsigned short)bf16r(a3[j]);
            }
            *(u16x4*)(smem + OFF_P + fs * 136 + (0 * 16 + lq * 4) * 2) = p0;
            *(u16x4*)(smem + OFF_P + fs * 136 + (1 * 16 + lq * 4) * 2) = p1;
            *(u16x4*)(smem + OFF_P + fs * 136 + (2 * 16 + lq * 4) * 2) = p2;
            *(u16x4*)(smem + OFF_P + fs * 136 + (3 * 16 + lq * 4) * 2) = p3;
        }
        if (fs >= 32) {
            int fm = fs - 32;
            u16x4 p4, p5;
            #pragma unroll
            for (int j = 0; j < 4; ++j) {
                p4[j] = (unsigned short)bf16r(a4[j]);
                p5[j] = (unsigned short)bf16r(a5[j]);
            }
            *(u16x4*)(smem + OFF_D + fm * 80 + (0 * 16 + lq * 4) * 2) = p4;
            *(u16x4*)(smem + OFF_D + fm * 80 + (1 * 16 + lq * 4) * 2) = p5;
        }
    }
    __syncthreads();

    // ================= conv1: 288 mid states -> h1 (bf16, W region) ==========
    {
        int c = tid & 31, g = tid >> 5;          // 32 groups x 9 frames
        float enu = expf(nu1[c]);
        float mag = expf(-enu);
        float ang = expf(th1[c]);
        float lr = mag * cosf(ang), li = mag * sinf(ang);
        float gam = sqrtf(fmaxf(1.0f - mag * mag, 0.0f));
        const float* lam = (const float*)(smem + OFF_LAM1);
        int fmb = g * 9;
        float hre = 0.f, him = 0.f;
        for (int j = 0; j < WU; ++j) {
            float2 lp = *(const float2*)(lam + j * 64 + 2 * c);
            unsigned uw = *(const unsigned*)(smem + OFF_P + (fmb + 32 - j) * 136 + c * 4);
            float ur = bf2f(uw & 0xFFFFu), ui = bf2f(uw >> 16);
            hre = fmaf(lp.x, ur, hre); hre = fmaf(-lp.y, ui, hre);
            him = fmaf(lp.x, ui, him); him = fmaf(lp.y, ur, him);
        }
        *(unsigned*)(smem + OFF_W + fmb * 144 + c * 4) = (bf16r(him) << 16) | bf16r(hre);
        for (int s = 1; s < 9; ++s) {
            unsigned uw = *(const unsigned*)(smem + OFF_P + (fmb + 32 + s) * 136 + c * 4);
            float ur = bf2f(uw & 0xFFFFu), ui = bf2f(uw >> 16);
            float nre = lr * hre - li * him + gam * ur;
            float nim = lr * him + li * hre + gam * ui;
            hre = nre; him = nim;
            *(unsigned*)(smem + OFF_W + (fmb + s) * 144 + c * 4) = (bf16r(him) << 16) | bf16r(hre);
        }
    }
    __syncthreads();

    // ================= GEMM2: y1 = C1cat @ h1 + d1x ; selu -> y1s (P) ========
    #pragma unroll 1
    for (int ci = w; ci < 36; ci += 16) {
        int n = ci >> 1, m = ci & 1;
        int fcol = n * 16 + l15;
        u16x4 dk = *(const u16x4*)(smem + OFF_D + fcol * 80 + (m * 16 + lq * 4) * 2);
        f32x4 c;
        #pragma unroll
        for (int j = 0; j < 4; ++j) c[j] = bf2f(dk[j]);
        #pragma unroll
        for (int ks = 0; ks < 2; ++ks) {
            bf16x8 ah = *(const bf16x8*)(smem + OFF_C1HI + (m * 16 + l15) * 144 + ks * 64 + lq * 16);
            bf16x8 bb = *(const bf16x8*)(smem + OFF_W + fcol * 144 + ks * 64 + lq * 16);
            c = __builtin_amdgcn_mfma_f32_16x16x32_bf16(ah, bb, c, 0, 0, 0);
        }
        u16x4 pk;
        #pragma unroll
        for (int j = 0; j < 4; ++j) pk[j] = (unsigned short)bf16r(selu_f(c[j]));
        *(u16x4*)(smem + OFF_P + fcol * 80 + (m * 16 + lq * 4) * 2) = pk;
    }
    __syncthreads();

    // ================= MLP: y2 = mlpw^T @ y1s + bias ; selu -> y2l (D) =======
    #pragma unroll 1
    for (int ci = w; ci < 36; ci += 16) {
        int n = ci >> 1, m = ci & 1;
        int fcol = n * 16 + l15;
        f32x4 c = *(const f32x4*)(smem + OFF_BIAS + (m * 16 + lq * 4) * 4);
        {
            bf16x8 ah = *(const bf16x8*)(smem + OFF_MWHI + (m * 16 + l15) * 80 + lq * 16);
            bf16x8 bb = *(const bf16x8*)(smem + OFF_P + fcol * 80 + lq * 16);
            c = __builtin_amdgcn_mfma_f32_16x16x32_bf16(ah, bb, c, 0, 0, 0);
        }
        u16x4 pk;
        #pragma unroll
        for (int j = 0; j < 4; ++j) pk[j] = (unsigned short)bf16r(selu_f(c[j]));
        *(u16x4*)(smem + OFF_D + fcol * 80 + (m * 16 + lq * 4) * 2) = pk;
    }
    __syncthreads();

    // ================= GEMM3: u2 = b2cat @ y2l -> u2s (P, bf16) ==============
    #pragma unroll 1
    for (int ci = w; ci < 72; ci += 16) {
        int n = ci >> 2, m = ci & 3;
        int fcol = n * 16 + l15;
        f32x4 c = f32x4{0.f, 0.f, 0.f, 0.f};
        {
            bf16x8 ah = *(const bf16x8*)(smem + OFF_B2HI + (m * 16 + l15) * 80 + lq * 16);
            bf16x8 bb = *(const bf16x8*)(smem + OFF_D + fcol * 80 + lq * 16);
            c = __builtin_amdgcn_mfma_f32_16x16x32_bf16(ah, bb, c, 0, 0, 0);
        }
        if (t0 - 32 + fcol < 0) c = f32x4{0.f, 0.f, 0.f, 0.f};   // pre-history is zero
        u16x4 pk;
        #pragma unroll
        for (int j = 0; j < 4; ++j) pk[j] = (unsigned short)bf16r(c[j]);
        *(u16x4*)(smem + OFF_P + fcol * 136 + (m * 16 + lq * 4) * 2) = pk;
    }
    __syncthreads();

    // ================= conv2: 256 out states -> h2 (bf16, W region) ==========
    {
        int c = tid & 31, g = tid >> 5;          // 32 groups x 8 frames
        float enu = expf(nu2[c]);
        float mag = expf(-enu);
        float ang = expf(th2[c]);
        float lr = mag * cosf(ang), li = mag * sinf(ang);
        float gam = sqrtf(fmaxf(1.0f - mag * mag, 0.0f));
        const float* lam = (const float*)(smem + OFF_LAM2);
        int fob = g * 8;
        float hre = 0.f, him = 0.f;
        for (int j = 0; j < WU; ++j) {
            float2 lp = *(const float2*)(lam + j * 64 + 2 * c);
            unsigned uw = *(const unsigned*)(smem + OFF_P + (fob + 32 - j) * 136 + c * 4);
            float ur = bf2f(uw & 0xFFFFu), ui = bf2f(uw >> 16);
            hre = fmaf(lp.x, ur, hre); hre = fmaf(-lp.y, ui, hre);
            him = fmaf(lp.x, ui, him); him = fmaf(lp.y, ur, him);
        }
        *(unsigned*)(smem + OFF_W + fob * 144 + c * 4) = (bf16r(him) << 16) | bf16r(hre);
        for (int s = 1; s < 8; ++s) {
            unsigned uw = *(const unsigned*)(smem + OFF_P + (fob + 32 + s) * 136 + c * 4);
            float ur = bf2f(uw & 0xFFFFu), ui = bf2f(uw >> 16);
            float nre = lr * hre - li * him + gam * ur;
            float nim = lr * him + li * hre + gam * ui;
            hre = nre; him = nim;
            *(unsigned*)(smem + OFF_W + (fob + s) * 144 + c * 4) = (bf16r(him) << 16) | bf16r(hre);
        }
    }
    __syncthreads();

    // ================= GEMM4: out = wcat @ [h2 ; y2] ==========================
    // wave w owns M-tile w (16 rows); wcat hi/lo preloaded; store-as-you-go.
    {
        const int row = w * 16 + l15;
        bf16x8 ah0 = *(const bf16x8*)(whi + row * 96 + 0 * 32 + lq * 8);
        bf16x8 ah1 = *(const bf16x8*)(whi + row * 96 + 1 * 32 + lq * 8);
        bf16x8 ah2 = *(const bf16x8*)(whi + row * 96 + 2 * 32 + lq * 8);
        bf16x8 al0 = *(const bf16x8*)(wlo + row * 96 + 0 * 32 + lq * 8);
        bf16x8 al1 = *(const bf16x8*)(wlo + row * 96 + 1 * 32 + lq * 8);
        bf16x8 al2 = *(const bf16x8*)(wlo + row * 96 + 2 * 32 + lq * 8);
        const int row0 = w * 16 + lq * 4;
        #pragma unroll 1
        for (int n = 0; n < 16; ++n) {
            int fcol = n * 16 + l15;
            f32x4 c = f32x4{0.f, 0.f, 0.f, 0.f};
            bf16x8 b0 = *(const bf16x8*)(smem + OFF_W + fcol * 144 + 0 * 64 + lq * 16);
            bf16x8 b1 = *(const bf16x8*)(smem + OFF_W + fcol * 144 + 1 * 64 + lq * 16);
            bf16x8 b2 = *(const bf16x8*)(smem + OFF_D + (fcol + 32) * 80 + lq * 16);
            c = __builtin_amdgcn_mfma_f32_16x16x32_bf16(ah0, b0, c, 0, 0, 0);
            c = __builtin_amdgcn_mfma_f32_16x16x32_bf16(al0, b0, c, 0, 0, 0);
            c = __builtin_amdgcn_mfma_f32_16x16x32_bf16(ah1, b1, c, 0, 0, 0);
            c = __builtin_amdgcn_mfma_f32_16x16x32_bf16(al1, b1, c, 0, 0, 0);
            c = __builtin_amdgcn_mfma_f32_16x16x32_bf16(ah2, b2, c, 0, 0, 0);
            c = __builtin_amdgcn_mfma_f32_16x16x32_bf16(al2, b2, c, 0, 0, 0);
            int t = t0 + n * 16 + l15;
            #pragma unroll
            for (int j = 0; j < 4; ++j)
                out[(size_t)(row0 + j) * LFRAMES + t] = c[j];
        }
    }
}

extern "C" void kernel_launch(void* const* d_in, const int* in_sizes, int n_in,
                              void* d_out, int out_size, void* d_ws, size_t ws_size,
                              hipStream_t stream)
{
    const float* x     = (const float*)d_in[0];
    const float* b1r   = (const float*)d_in[1];
    const float* b1i   = (const float*)d_in[2];
    const float* nu1   = (const float*)d_in[3];
    const float* th1   = (const float*)d_in[4];
    const float* c1r   = (const float*)d_in[5];
    const float* c1i   = (const float*)d_in[6];
    const float* d1    = (const float*)d_in[7];
    const float* mlp_w = (const float*)d_in[8];
    const float* mlp_b = (const float*)d_in[9];
    const float* b2r   = (const float*)d_in[10];
    const float* b2i   = (const float*)d_in[11];
    const float* nu2   = (const float*)d_in[12];
    const float* th2   = (const float*)d_in[13];
    const float* c2r   = (const float*)d_in[14];
    const float* c2i   = (const float*)d_in[15];
    const float* d2    = (const float*)d_in[16];
    float* out = (float*)d_out;

    unsigned short* whi = (unsigned short*)d_ws;                      // 49,152 B
    unsigned short* wlo = (unsigned short*)((char*)d_ws + 49152);     // 49,152 B

    prep_wcat<<<dim3((O2 * 96 + 255) / 256), dim3(256), 0, stream>>>(c2r, c2i, d2, whi, wlo);

    lru_fused<<<dim3(LFRAMES / FO_BLK), dim3(1024), 0, stream>>>(
        x, b1r, b1i, nu1, th1, c1r, c1i, d1, mlp_w, mlp_b,
        b2r, b2i, nu2, th2, whi, wlo, out);
}

// Round 8
// 42.539 us; speedup vs baseline: 1.9541x; 1.0797x over previous
//
#include <hip/hip_runtime.h>

#define WINDOW 128
#define H 32
#define O2 256
#define LFRAMES 65536
#define WU 32
#define FO_BLK 128     // output frames per block
#define FM 160         // mid (y-chain) frames per block
#define FS 192         // staged x frames per block

using bf16x8 = __attribute__((ext_vector_type(8))) short;
using f32x4  = __attribute__((ext_vector_type(4))) float;
using u16x4  = __attribute__((ext_vector_type(4))) unsigned short;

__device__ __forceinline__ unsigned bf16r(float v) {   // RTNE float->bf16 bits
    unsigned u = __builtin_bit_cast(unsigned, v);
    return (u + 0x7FFFu + ((u >> 16) & 1u)) >> 16;
}
__device__ __forceinline__ float bf2f(unsigned s) {
    return __builtin_bit_cast(float, s << 16);
}
__device__ __forceinline__ float selu_f(float x) {
    const float scale = 1.0507009873554805f;
    const float alpha = 1.6732632423543772f;
    return scale * (x > 0.0f ? x : alpha * (expf(x) - 1.0f));
}
__device__ __forceinline__ bf16x8 cvt8(float4 a, float4 b) {
    bf16x8 r;
    r[0] = (short)bf16r(a.x); r[1] = (short)bf16r(a.y);
    r[2] = (short)bf16r(a.z); r[3] = (short)bf16r(a.w);
    r[4] = (short)bf16r(b.x); r[5] = (short)bf16r(b.y);
    r[6] = (short)bf16r(b.z); r[7] = (short)bf16r(b.w);
    return r;
}

// ---------------- LDS byte offsets (total 77440 -> 2 blocks/CU) -------------
#define OFF_C1HI   0        // [32] pitch 144B                 (4608)
#define OFF_MWHI   4608     // [32] pitch 80B                  (2560)
#define OFF_B2HI   7168     // [64] pitch 80B                  (5120)
#define OFF_BIAS   12288    // [32] f32                        (128)
#define OFF_P      12416    // u1 [192]p136 (26112) | y1s [160]p80 | u2s [160]p136
#define OFF_D      38528    // d1x [160]p80 (12800) | y2l [160]p80
#define OFF_W      51328    // W1HI [96]p272 (26112) | h1 [160]p144 | h2 [128]p144
#define S_LDS      77440

// ---------------- ws element offsets (shorts) --------------------------------
// w1hi [96*128] | c1hi [32*64] | mwhi [32*32] | b2hi [64*32] | wchi | wclo
#define WS_W1   0
#define WS_C1   12288
#define WS_MW   14336
#define WS_B2   15360
#define WS_WC   17408
#define WS_WCLO 41984
#define WS_TOT  66560

// ---------------------------------------------------------------------------
// prep: all weights pre-converted to bf16 (hi; wcat also lo) in ws.
// ---------------------------------------------------------------------------
__global__ void prep_weights(const float* __restrict__ b1r, const float* __restrict__ b1i,
                             const float* __restrict__ d1,
                             const float* __restrict__ c1r, const float* __restrict__ c1i,
                             const float* __restrict__ mlp_w,
                             const float* __restrict__ b2r, const float* __restrict__ b2i,
                             const float* __restrict__ c2r, const float* __restrict__ c2i,
                             const float* __restrict__ d2,
                             unsigned short* __restrict__ ws)
{
    int idx = blockIdx.x * 256 + threadIdx.x;
    if (idx < WS_C1) {                       // W1: 0..63 interleaved b1r/b1i, 64..95 d1
        int row = idx >> 7, k = idx & 127;
        float v;
        if (row < 64) v = (row & 1) ? b1i[(row >> 1) * WINDOW + k] : b1r[(row >> 1) * WINDOW + k];
        else          v = d1[(row - 64) * WINDOW + k];
        ws[WS_W1 + idx] = (unsigned short)bf16r(v);
    } else if (idx < WS_MW) {                // C1cat: k even -> c1r, k odd -> -c1i
        int j = idx - WS_C1;
        int row = j >> 6, k = j & 63;
        float v = (k & 1) ? -c1i[row * H + (k >> 1)] : c1r[row * H + (k >> 1)];
        ws[idx] = (unsigned short)bf16r(v);
    } else if (idx < WS_B2) {                // mlpw^T
        int j = idx - WS_MW;
        int row = j >> 5, k = j & 31;
        ws[idx] = (unsigned short)bf16r(mlp_w[k * H + row]);
    } else if (idx < WS_WC) {                // b2cat interleaved
        int j = idx - WS_B2;
        int row = j >> 5, k = j & 31;
        float v = (row & 1) ? b2i[(row >> 1) * H + k] : b2r[(row >> 1) * H + k];
        ws[idx] = (unsigned short)bf16r(v);
    } else if (idx < WS_WCLO) {              // wcat hi + lo
        int j = idx - WS_WC;
        int row = j / 96, k = j - row * 96;
        float v;
        if (k < 64) v = (k & 1) ? -c2i[row * H + (k >> 1)] : c2r[row * H + (k >> 1)];
        else        v = d2[row * H + (k - 64)];
        unsigned h = bf16r(v);
        ws[WS_WC + j]   = (unsigned short)h;
        ws[WS_WCLO + j] = (unsigned short)bf16r(v - bf2f(h));
    }
}

// ---------------------------------------------------------------------------
// Fused kernel: 512 blocks x 1024 threads, 2 blocks/CU (32 waves/CU).
// ---------------------------------------------------------------------------
__global__ __launch_bounds__(1024, 8)
void lru_fused(const float* __restrict__ x,
               const float* __restrict__ nu1, const float* __restrict__ th1,
               const float* __restrict__ nu2, const float* __restrict__ th2,
               const float* __restrict__ mlp_b,
               const unsigned short* __restrict__ ws,
               float* __restrict__ out)
{
    __shared__ __align__(16) char smem[S_LDS];
    const int tid = threadIdx.x;
    const int t0 = blockIdx.x * FO_BLK;
    const int frame0 = t0 - 64;              // global frame of staged idx 0
    const int w = tid >> 6, l = tid & 63, l15 = l & 15, lq = l >> 4;

    // ================= phase 0: copy pre-converted weights -> LDS ============
    {   // W1: [96][128] -> pitch 272B
        #pragma unroll
        for (int p = 0; p < 3; ++p) {
            int idx = tid + 1024 * p;
            int row = idx >> 5, c4 = idx & 31;
            u16x4 v = *(const u16x4*)(ws + WS_W1 + row * 128 + c4 * 4);
            *(u16x4*)(smem + OFF_W + row * 272 + c4 * 8) = v;
        }
    }
    if (tid < 512) {       // C1cat: [32][64] -> pitch 144B
        int row = tid >> 4, c4 = tid & 15;
        u16x4 v = *(const u16x4*)(ws + WS_C1 + row * 64 + c4 * 4);
        *(u16x4*)(smem + OFF_C1HI + row * 144 + c4 * 8) = v;
    } else {               // b2cat: [64][32] -> pitch 80B
        int j = tid - 512;
        int row = j >> 3, c4 = j & 7;
        u16x4 v = *(const u16x4*)(ws + WS_B2 + row * 32 + c4 * 4);
        *(u16x4*)(smem + OFF_B2HI + row * 80 + c4 * 8) = v;
    }
    if (tid < 256) {       // mlpw^T: [32][32] -> pitch 80B
        int row = tid >> 3, c4 = tid & 7;
        u16x4 v = *(const u16x4*)(ws + WS_MW + row * 32 + c4 * 4);
        *(u16x4*)(smem + OFF_MWHI + row * 80 + c4 * 8) = v;
    } else if (tid >= 256 && tid < 288) {
        ((float*)(smem + OFF_BIAS))[tid - 256] = mlp_b[tid - 256];
    }
    __syncthreads();

    // ================= GEMM1: U1 (96 x 192) = W1 @ X =========================
    // 12 N-tiles; waves 0..11 one tile each.
    if (w < 12) {
        const int nt = w;
        f32x4 a0 = f32x4{0.f,0.f,0.f,0.f}, a1 = a0, a2 = a0, a3 = a0, a4 = a0, a5 = a0;
        int gf = frame0 + nt * 16 + l15;
        const float4* xp = (const float4*)(x + (size_t)gf * WINDOW + lq * 8);
        #pragma unroll
        for (int ks = 0; ks < 4; ++ks) {
            float4 xa{}, xb{};
            if (gf >= 0) { xa = xp[ks * 8]; xb = xp[ks * 8 + 1]; }
            bf16x8 b = cvt8(xa, xb);
            bf16x8 w0 = *(const bf16x8*)(smem + OFF_W + (0 * 16 + l15) * 272 + ks * 64 + lq * 16);
            bf16x8 w1 = *(const bf16x8*)(smem + OFF_W + (1 * 16 + l15) * 272 + ks * 64 + lq * 16);
            bf16x8 w2 = *(const bf16x8*)(smem + OFF_W + (2 * 16 + l15) * 272 + ks * 64 + lq * 16);
            bf16x8 w3 = *(const bf16x8*)(smem + OFF_W + (3 * 16 + l15) * 272 + ks * 64 + lq * 16);
            bf16x8 w4 = *(const bf16x8*)(smem + OFF_W + (4 * 16 + l15) * 272 + ks * 64 + lq * 16);
            bf16x8 w5 = *(const bf16x8*)(smem + OFF_W + (5 * 16 + l15) * 272 + ks * 64 + lq * 16);
            a0 = __builtin_amdgcn_mfma_f32_16x16x32_bf16(w0, b, a0, 0, 0, 0);
            a1 = __builtin_amdgcn_mfma_f32_16x16x32_bf16(w1, b, a1, 0, 0, 0);
            a2 = __builtin_amdgcn_mfma_f32_16x16x32_bf16(w2, b, a2, 0, 0, 0);
            a3 = __builtin_amdgcn_mfma_f32_16x16x32_bf16(w3, b, a3, 0, 0, 0);
            a4 = __builtin_amdgcn_mfma_f32_16x16x32_bf16(w4, b, a4, 0, 0, 0);
            a5 = __builtin_amdgcn_mfma_f32_16x16x32_bf16(w5, b, a5, 0, 0, 0);
        }
        int fs = nt * 16 + l15;
        {
            u16x4 p0, p1, p2, p3;
            #pragma unroll
            for (int j = 0; j < 4; ++j) {
                p0[j] = (unsigned short)bf16r(a0[j]);
                p1[j] = (unsigned short)bf16r(a1[j]);
                p2[j] = (unsigned short)bf16r(a2[j]);
                p3[j] = (unsigned short)bf16r(a3[j]);
            }
            *(u16x4*)(smem + OFF_P + fs * 136 + (0 * 16 + lq * 4) * 2) = p0;
            *(u16x4*)(smem + OFF_P + fs * 136 + (1 * 16 + lq * 4) * 2) = p1;
            *(u16x4*)(smem + OFF_P + fs * 136 + (2 * 16 + lq * 4) * 2) = p2;
            *(u16x4*)(smem + OFF_P + fs * 136 + (3 * 16 + lq * 4) * 2) = p3;
        }
        if (fs >= 32) {
            int fm = fs - 32;
            u16x4 p4, p5;
            #pragma unroll
            for (int j = 0; j < 4; ++j) {
                p4[j] = (unsigned short)bf16r(a4[j]);
                p5[j] = (unsigned short)bf16r(a5[j]);
            }
            *(u16x4*)(smem + OFF_D + fm * 80 + (0 * 16 + lq * 4) * 2) = p4;
            *(u16x4*)(smem + OFF_D + fm * 80 + (1 * 16 + lq * 4) * 2) = p5;
        }
    }
    __syncthreads();

    // ================= conv1: 160 mid states -> h1 (bf16, W region) ==========
    {
        int c = tid & 31, g = tid >> 5;          // 32 groups x 5 frames
        float enu = expf(nu1[c]);
        float mag = expf(-enu);
        float ang = expf(th1[c]);
        float lr = mag * cosf(ang), li = mag * sinf(ang);
        float gam = sqrtf(fmaxf(1.0f - mag * mag, 0.0f));
        int fmb = g * 5;
        float hre = 0.f, him = 0.f;
        float pr = gam, pi = 0.f;                // gamma * lam^j on the fly
        for (int j = 0; j < WU; ++j) {
            unsigned uw = *(const unsigned*)(smem + OFF_P + (fmb + 32 - j) * 136 + c * 4);
            float ur = bf2f(uw & 0xFFFFu), ui = bf2f(uw >> 16);
            hre = fmaf(pr, ur, hre); hre = fmaf(-pi, ui, hre);
            him = fmaf(pr, ui, him); him = fmaf(pi, ur, him);
            float npr = pr * lr - pi * li, npi = pr * li + pi * lr;
            pr = npr; pi = npi;
        }
        *(unsigned*)(smem + OFF_W + fmb * 144 + c * 4) = (bf16r(him) << 16) | bf16r(hre);
        #pragma unroll
        for (int s = 1; s < 5; ++s) {
            unsigned uw = *(const unsigned*)(smem + OFF_P + (fmb + 32 + s) * 136 + c * 4);
            float ur = bf2f(uw & 0xFFFFu), ui = bf2f(uw >> 16);
            float nre = lr * hre - li * him + gam * ur;
            float nim = lr * him + li * hre + gam * ui;
            hre = nre; him = nim;
            *(unsigned*)(smem + OFF_W + (fmb + s) * 144 + c * 4) = (bf16r(him) << 16) | bf16r(hre);
        }
    }
    __syncthreads();

    // ================= GEMM2: y1 = C1cat @ h1 + d1x ; selu -> y1s (P) ========
    #pragma unroll 1
    for (int ci = w; ci < 20; ci += 16) {
        int n = ci >> 1, m = ci & 1;
        int fcol = n * 16 + l15;
        u16x4 dk = *(const u16x4*)(smem + OFF_D + fcol * 80 + (m * 16 + lq * 4) * 2);
        f32x4 c;
        #pragma unroll
        for (int j = 0; j < 4; ++j) c[j] = bf2f(dk[j]);
        #pragma unroll
        for (int ks = 0; ks < 2; ++ks) {
            bf16x8 ah = *(const bf16x8*)(smem + OFF_C1HI + (m * 16 + l15) * 144 + ks * 64 + lq * 16);
            bf16x8 bb = *(const bf16x8*)(smem + OFF_W + fcol * 144 + ks * 64 + lq * 16);
            c = __builtin_amdgcn_mfma_f32_16x16x32_bf16(ah, bb, c, 0, 0, 0);
        }
        u16x4 pk;
        #pragma unroll
        for (int j = 0; j < 4; ++j) pk[j] = (unsigned short)bf16r(selu_f(c[j]));
        *(u16x4*)(smem + OFF_P + fcol * 80 + (m * 16 + lq * 4) * 2) = pk;
    }
    __syncthreads();

    // ================= MLP: y2 = mlpw^T @ y1s + bias ; selu -> y2l (D) =======
    #pragma unroll 1
    for (int ci = w; ci < 20; ci += 16) {
        int n = ci >> 1, m = ci & 1;
        int fcol = n * 16 + l15;
        f32x4 c = *(const f32x4*)(smem + OFF_BIAS + (m * 16 + lq * 4) * 4);
        {
            bf16x8 ah = *(const bf16x8*)(smem + OFF_MWHI + (m * 16 + l15) * 80 + lq * 16);
            bf16x8 bb = *(const bf16x8*)(smem + OFF_P + fcol * 80 + lq * 16);
            c = __builtin_amdgcn_mfma_f32_16x16x32_bf16(ah, bb, c, 0, 0, 0);
        }
        u16x4 pk;
        #pragma unroll
        for (int j = 0; j < 4; ++j) pk[j] = (unsigned short)bf16r(selu_f(c[j]));
        *(u16x4*)(smem + OFF_D + fcol * 80 + (m * 16 + lq * 4) * 2) = pk;
    }
    __syncthreads();

    // ================= GEMM3: u2 = b2cat @ y2l -> u2s (P, bf16) ==============
    #pragma unroll 1
    for (int ci = w; ci < 40; ci += 16) {
        int n = ci >> 2, m = ci & 3;
        int fcol = n * 16 + l15;
        f32x4 c = f32x4{0.f, 0.f, 0.f, 0.f};
        {
            bf16x8 ah = *(const bf16x8*)(smem + OFF_B2HI + (m * 16 + l15) * 80 + lq * 16);
            bf16x8 bb = *(const bf16x8*)(smem + OFF_D + fcol * 80 + lq * 16);
            c = __builtin_amdgcn_mfma_f32_16x16x32_bf16(ah, bb, c, 0, 0, 0);
        }
        if (t0 - 32 + fcol < 0) c = f32x4{0.f, 0.f, 0.f, 0.f};   // pre-history is zero
        u16x4 pk;
        #pragma unroll
        for (int j = 0; j < 4; ++j) pk[j] = (unsigned short)bf16r(c[j]);
        *(u16x4*)(smem + OFF_P + fcol * 136 + (m * 16 + lq * 4) * 2) = pk;
    }
    __syncthreads();

    // ================= conv2: 128 out states -> h2 (bf16, W region) ==========
    {
        int c = tid & 31, g = tid >> 5;          // 32 groups x 4 frames
        float enu = expf(nu2[c]);
        float mag = expf(-enu);
        float ang = expf(th2[c]);
        float lr = mag * cosf(ang), li = mag * sinf(ang);
        float gam = sqrtf(fmaxf(1.0f - mag * mag, 0.0f));
        int fob = g * 4;
        float hre = 0.f, him = 0.f;
        float pr = gam, pi = 0.f;
        for (int j = 0; j < WU; ++j) {
            unsigned uw = *(const unsigned*)(smem + OFF_P + (fob + 32 - j) * 136 + c * 4);
            float ur = bf2f(uw & 0xFFFFu), ui = bf2f(uw >> 16);
            hre = fmaf(pr, ur, hre); hre = fmaf(-pi, ui, hre);
            him = fmaf(pr, ui, him); him = fmaf(pi, ur, him);
            float npr = pr * lr - pi * li, npi = pr * li + pi * lr;
            pr = npr; pi = npi;
        }
        *(unsigned*)(smem + OFF_W + fob * 144 + c * 4) = (bf16r(him) << 16) | bf16r(hre);
        #pragma unroll
        for (int s = 1; s < 4; ++s) {
            unsigned uw = *(const unsigned*)(smem + OFF_P + (fob + 32 + s) * 136 + c * 4);
            float ur = bf2f(uw & 0xFFFFu), ui = bf2f(uw >> 16);
            float nre = lr * hre - li * him + gam * ur;
            float nim = lr * him + li * hre + gam * ui;
            hre = nre; him = nim;
            *(unsigned*)(smem + OFF_W + (fob + s) * 144 + c * 4) = (bf16r(him) << 16) | bf16r(hre);
        }
    }
    __syncthreads();

    // ================= GEMM4: out = wcat @ [h2 ; y2] ==========================
    // wave w owns M-tile w (16 rows); wcat hi/lo preloaded; store-as-you-go.
    {
        const unsigned short* whi = ws + WS_WC;
        const unsigned short* wlo = ws + WS_WCLO;
        const int row = w * 16 + l15;
        bf16x8 ah0 = *(const bf16x8*)(whi + row * 96 + 0 * 32 + lq * 8);
        bf16x8 ah1 = *(const bf16x8*)(whi + row * 96 + 1 * 32 + lq * 8);
        bf16x8 ah2 = *(const bf16x8*)(whi + row * 96 + 2 * 32 + lq * 8);
        bf16x8 al0 = *(const bf16x8*)(wlo + row * 96 + 0 * 32 + lq * 8);
        bf16x8 al1 = *(const bf16x8*)(wlo + row * 96 + 1 * 32 + lq * 8);
        bf16x8 al2 = *(const bf16x8*)(wlo + row * 96 + 2 * 32 + lq * 8);
        const int row0 = w * 16 + lq * 4;
        #pragma unroll 1
        for (int n = 0; n < 8; ++n) {
            int fcol = n * 16 + l15;
            f32x4 c = f32x4{0.f, 0.f, 0.f, 0.f};
            bf16x8 b0 = *(const bf16x8*)(smem + OFF_W + fcol * 144 + 0 * 64 + lq * 16);
            bf16x8 b1 = *(const bf16x8*)(smem + OFF_W + fcol * 144 + 1 * 64 + lq * 16);
            bf16x8 b2 = *(const bf16x8*)(smem + OFF_D + (fcol + 32) * 80 + lq * 16);
            c = __builtin_amdgcn_mfma_f32_16x16x32_bf16(ah0, b0, c, 0, 0, 0);
            c = __builtin_amdgcn_mfma_f32_16x16x32_bf16(al0, b0, c, 0, 0, 0);
            c = __builtin_amdgcn_mfma_f32_16x16x32_bf16(ah1, b1, c, 0, 0, 0);
            c = __builtin_amdgcn_mfma_f32_16x16x32_bf16(al1, b1, c, 0, 0, 0);
            c = __builtin_amdgcn_mfma_f32_16x16x32_bf16(ah2, b2, c, 0, 0, 0);
            c = __builtin_amdgcn_mfma_f32_16x16x32_bf16(al2, b2, c, 0, 0, 0);
            int t = t0 + n * 16 + l15;
            #pragma unroll
            for (int j = 0; j < 4; ++j)
                out[(size_t)(row0 + j) * LFRAMES + t] = c[j];
        }
    }
}

extern "C" void kernel_launch(void* const* d_in, const int* in_sizes, int n_in,
                              void* d_out, int out_size, void* d_ws, size_t ws_size,
                              hipStream_t stream)
{
    const float* x     = (const float*)d_in[0];
    const float* b1r   = (const float*)d_in[1];
    const float* b1i   = (const float*)d_in[2];
    const float* nu1   = (const float*)d_in[3];
    const float* th1   = (const float*)d_in[4];
    const float* c1r   = (const float*)d_in[5];
    const float* c1i   = (const float*)d_in[6];
    const float* d1    = (const float*)d_in[7];
    const float* mlp_w = (const float*)d_in[8];
    const float* mlp_b = (const float*)d_in[9];
    const float* b2r   = (const float*)d_in[10];
    const float* b2i   = (const float*)d_in[11];
    const float* nu2   = (const float*)d_in[12];
    const float* th2   = (const float*)d_in[13];
    const float* c2r   = (const float*)d_in[14];
    const float* c2i   = (const float*)d_in[15];
    const float* d2    = (const float*)d_in[16];
    float* out = (float*)d_out;

    unsigned short* ws = (unsigned short*)d_ws;   // 133,120 B

    prep_weights<<<dim3((WS_TOT + 255) / 256), dim3(256), 0, stream>>>(
        b1r, b1i, d1, c1r, c1i, mlp_w, b2r, b2i, c2r, c2i, d2, ws);

    lru_fused<<<dim3(LFRAMES / FO_BLK), dim3(1024), 0, stream>>>(
        x, nu1, th1, nu2, th2, mlp_b, ws, out);
}